// Round 9
// baseline (1051.384 us; speedup 1.0000x reference)
//
#include <hip/hip_runtime.h>
#include <hip/hip_bf16.h>

// Problem constants
#define BB 16
#define LL 1024
#define DD 384
#define FF 1536
#define KK 3
#define T_OUT 10240
#define MAX_DUR 10

#define PADL 1026                 // per-batch padded rows: [0]=zero, [1..1024]=data, [1025]=zero
#define LO_SCALE 2048.0f          // 2^11: keeps lo parts out of fp16-denormal range
#define LO_INV   4.8828125e-4f    // 2^-11

typedef _Float16 f16x8 __attribute__((ext_vector_type(8)));
typedef float    f32x4 __attribute__((ext_vector_type(4)));

__device__ __forceinline__ void gll16(const void* g, void* l) {
    __builtin_amdgcn_global_load_lds(
        (const __attribute__((address_space(1))) void*)g,
        (__attribute__((address_space(3))) void*)l, 16, 0, 0);
}

__device__ __forceinline__ void split_write(float v, _Float16* hi, _Float16* lo, size_t off) {
    _Float16 h = (_Float16)v;
    hi[off] = h;
    lo[off] = (_Float16)((v - (float)h) * LO_SCALE);
}

__device__ __forceinline__ float split_read(const _Float16* hi, const _Float16* lo, size_t off) {
    return (float)hi[off] + (float)lo[off] * LO_INV;
}

// ---- fused weight pack: 4 weights -> MFMA-fragment-major hi/lo -------------
// frag layout: [o_tile16][ktl][lane][e8]; ktl order: kseg=ktl%3, d0=(ktl/3)*32
__global__ void prep_w(const float* __restrict__ w1a, const float* __restrict__ w1b,
                       const float* __restrict__ w2a, const float* __restrict__ w2b,
                       _Float16* __restrict__ base) {
    const int total = FF * 3 * DD;               // same count for all 4
    int id = blockIdx.x * 256 + threadIdx.x;
    int which = id / total;
    int rid = id - which * total;
    if (which >= 4) return;
    const float* w; _Float16 *hi, *lo; int I;
    const size_t WN = (size_t)FF * DD * KK;
    if (which == 0)      { w = w1a; I = DD; hi = base;          lo = base + WN; }
    else if (which == 1) { w = w1b; I = FF; hi = base + 2 * WN; lo = base + 3 * WN; }
    else if (which == 2) { w = w2a; I = DD; hi = base + 4 * WN; lo = base + 5 * WN; }
    else                 { w = w2b; I = FF; hi = base + 6 * WN; lo = base + 7 * WN; }
    int e = rid & 7;
    int lane = (rid >> 3) & 63;
    int rest = rid >> 9;
    int nKT = (3 * I) >> 5;
    int ktl = rest % nKT;
    int ot = rest / nKT;
    int o = ot * 16 + (lane & 15);
    int koff = ((lane >> 4) << 3) + e;
    int kseg = ktl % 3;
    int i = (ktl / 3) * 32 + koff;
    float v = w[(o * I + i) * 3 + kseg];
    split_write(v, hi, lo, rid);
}

// ---- fused: y split into padded hi/lo + zero H1 halo rows ------------------
__global__ void prep_y(const float* __restrict__ y, _Float16* __restrict__ shi,
                       _Float16* __restrict__ slo, _Float16* __restrict__ h1hi,
                       _Float16* __restrict__ h1lo) {
    const int SNc = BB * PADL * DD;
    int id = blockIdx.x * 256 + threadIdx.x;
    if (id < SNc) {
        int d = id % DD;
        int r = id / DD;
        int b = r / PADL;
        int lr = r - b * PADL;
        float v = 0.f;
        if (lr >= 1 && lr <= LL) v = y[((size_t)(b << 10) + (lr - 1)) * DD + d];
        split_write(v, shi, slo, id);
        return;
    }
    int id2 = id - SNc;                          // BB*2*FF halo elements of H1
    if (id2 >= BB * 2 * FF) return;
    int b = id2 / (2 * FF);
    int rem = id2 - b * 2 * FF;
    int row = (rem / FF) ? (PADL - 1) : 0;
    int c = rem % FF;
    size_t off = (size_t)(b * PADL + row) * FF + c;
    h1hi[off] = (_Float16)0.f;
    h1lo[off] = (_Float16)0.f;
}

// ---------------- split-fp16 MFMA conv-GEMM (R4 config, proven 883 TF) -------
// 128x128 block, 4 waves of 64x64, BK=32, 32 KB LDS double buffer for A,
// B direct global->reg from fragment-major pack.
// Split-K: grid = nHalf*blocksPerHalf; half h does k-tiles [h*nKTper,
// (h+1)*nKTper), writes raw partial (doRelu=0) to Ohi/Olo + h*halfStride.
__global__ __launch_bounds__(256, 2) void gemm_split(
        const _Float16* __restrict__ Ahi, const _Float16* __restrict__ Alo,
        const _Float16* __restrict__ WfH, const _Float16* __restrict__ WfL,
        const float* __restrict__ bias,
        _Float16* __restrict__ Ohi, _Float16* __restrict__ Olo,
        size_t halfStride,
        int Cin, int Cout, int nKTper, int nN, int blocksPerHalf, int doRelu) {
    __shared__ _Float16 lds_h[16384];   // 32 KB: 2 x (Ahi 8KB | Alo 8KB)
    const int tid = threadIdx.x;
    const int lane = tid & 63;
    const int w = tid >> 6;
    const int lm = lane & 15, lq = lane >> 4;
    const int nKTfull = (3 * Cin) >> 5;
    // half decode + XCD-aware remap (group-of-4 m-tiles, n fastest)
    const int half = blockIdx.x / blocksPerHalf;
    const int t2in = blockIdx.x - half * blocksPerHalf;
    const int xcd = t2in & 7;
    const int t2 = t2in >> 3;
    const int g  = t2 / (4 * nN);
    const int r  = t2 - g * (4 * nN);
    const int n_t = r >> 2;
    const int mi  = r & 3;
    const int m_t = ((g * 4 + mi) << 3) + xcd;
    const int m0 = m_t << 7;
    const int n0 = n_t << 7;
    const int b = m0 >> 10;
    const int l0 = m0 & 1023;
    const int rowBase = b * PADL + l0;           // + m + kseg = padded source row
    const int wm = (w >> 1) * 64, wn = (w & 1) * 64;
    const int ktBegin = half * nKTper;
    const int ktEnd = ktBegin + nKTper;

    f32x4 accM[4][4], accC[4][4];
    const f32x4 zz = {0.f, 0.f, 0.f, 0.f};
    #pragma unroll
    for (int i = 0; i < 4; ++i)
        #pragma unroll
        for (int jj = 0; jj < 4; ++jj) { accM[i][jj] = zz; accC[i][jj] = zz; }

    // stage A k-tile kt into LDS buffer nxt (512 16B-slots per comp)
    auto stageA = [&](int kt, int nxt) {
        int kseg = kt % 3;
        int d0 = (kt / 3) << 5;
        #pragma unroll
        for (int it = 0; it < 2; ++it) {
            int s = (w * 2 + it) * 64 + lane;    // 16B-slot index 0..511
            int p = s >> 3, sl = s & 7;
            int t = sl ^ (p & 7);
            int m = p * 2 + (t >> 2);
            int k8 = t & 3;
            size_t aoff = (size_t)(rowBase + m + kseg) * Cin + d0 + k8 * 8;
            _Float16* lbase = lds_h + nxt * 8192 + (size_t)(w * 2 + it) * 512;
            gll16(Ahi + aoff, lbase);
            gll16(Alo + aoff, lbase + 4096);
        }
    };

    stageA(ktBegin, 0);
    for (int kt = ktBegin; kt < ktEnd; ++kt) {
        const int cur = (kt - ktBegin) & 1;
        __syncthreads();                          // buf[cur] staged; prior reads of buf[cur^1] done
        // B fragments for this k-tile: direct global->register, coalesced
        f16x8 bH[4], bL[4];
        #pragma unroll
        for (int jj = 0; jj < 4; ++jj) {
            int ntg = (n0 + wn + jj * 16) >> 4;
            size_t boff = (((size_t)ntg * nKTfull + kt) * 64 + lane) * 8;
            bH[jj] = *(const f16x8*)(WfH + boff);
            bL[jj] = *(const f16x8*)(WfL + boff);
        }
        if (kt + 1 < ktEnd) stageA(kt + 1, cur ^ 1);
        const _Float16* lb = lds_h + cur * 8192;
        f16x8 aH[4], aL[4];
        #pragma unroll
        for (int i = 0; i < 4; ++i) {
            int m = wm + i * 16 + lm;
            int p = m >> 1;
            int sl = (((m & 1) << 2) | lq) ^ (p & 7);
            int off = p * 64 + sl * 8;
            aH[i] = *(const f16x8*)(lb + off);
            aL[i] = *(const f16x8*)(lb + 4096 + off);
        }
        #pragma unroll
        for (int jj = 0; jj < 4; ++jj)            // j-outer: consume earliest load first
            #pragma unroll
            for (int i = 0; i < 4; ++i) {
                accM[i][jj] = __builtin_amdgcn_mfma_f32_16x16x32_f16(aH[i], bH[jj], accM[i][jj], 0, 0, 0);
                accC[i][jj] = __builtin_amdgcn_mfma_f32_16x16x32_f16(aH[i], bL[jj], accC[i][jj], 0, 0, 0);
                accC[i][jj] = __builtin_amdgcn_mfma_f32_16x16x32_f16(aL[i], bH[jj], accC[i][jj], 0, 0, 0);
            }
    }
    // epilogue: (bias+relu | raw partial) re-split to padded hi/lo output
    _Float16* oh = Ohi + (size_t)half * halfStride;
    _Float16* ol = Olo + (size_t)half * halfStride;
    #pragma unroll
    for (int i = 0; i < 4; ++i)
        #pragma unroll
        for (int jj = 0; jj < 4; ++jj) {
            int n_g = n0 + wn + jj * 16 + lm;
            float bv = doRelu ? bias[n_g] : 0.f;
            #pragma unroll
            for (int rr = 0; rr < 4; ++rr) {
                int l = l0 + wm + i * 16 + lq * 4 + rr;
                float v = accM[i][jj][rr] + accC[i][jj][rr] * LO_INV + bv;
                if (doRelu) v = fmaxf(v, 0.f);
                size_t off = (size_t)(b * PADL + 1 + l) * Cout + n_g;
                split_write(v, oh, ol, off);
            }
        }
}

// ---- split-K(4) reduce + bias + relu + LayerNorm -> S ----------------------
__global__ __launch_bounds__(128) void reduce_ln_k(
        const _Float16* __restrict__ Pbase, size_t halfStride,
        _Float16* __restrict__ Shi, _Float16* __restrict__ Slo,
        const float* __restrict__ bias, const float* __restrict__ g,
        const float* __restrict__ be) {
    const int row = blockIdx.x;
    const int b = row >> 10, l = row & 1023;
    const size_t SNc = (size_t)BB * PADL * DD;
    const size_t base = (size_t)(b * PADL + 1 + l) * DD;
    const int tid = threadIdx.x;
    float v0 = bias[tid], v1 = bias[tid + 128], v2 = bias[tid + 256];
    #pragma unroll
    for (int h = 0; h < 4; ++h) {
        const _Float16* ph = Pbase + (size_t)h * halfStride;
        const _Float16* pl = ph + SNc;
        v0 += split_read(ph, pl, base + tid);
        v1 += split_read(ph, pl, base + tid + 128);
        v2 += split_read(ph, pl, base + tid + 256);
    }
    v0 = fmaxf(v0, 0.f); v1 = fmaxf(v1, 0.f); v2 = fmaxf(v2, 0.f);

    __shared__ float sh[2];
    float s = v0 + v1 + v2;
    #pragma unroll
    for (int o = 32; o > 0; o >>= 1) s += __shfl_down(s, o, 64);
    if ((tid & 63) == 0) sh[tid >> 6] = s;
    __syncthreads();
    float mu = (sh[0] + sh[1]) * (1.f / DD);
    __syncthreads();
    float d0 = v0 - mu, d1 = v1 - mu, d2 = v2 - mu;
    float q = d0 * d0 + d1 * d1 + d2 * d2;
    #pragma unroll
    for (int o = 32; o > 0; o >>= 1) q += __shfl_down(q, o, 64);
    if ((tid & 63) == 0) sh[tid >> 6] = q;
    __syncthreads();
    float var = (sh[0] + sh[1]) * (1.f / DD);
    float rs = rsqrtf(var + 1e-5f);
    split_write(d0 * rs * g[tid] + be[tid], Shi, Slo, base + tid);
    split_write(d1 * rs * g[tid + 128] + be[tid + 128], Shi, Slo, base + tid + 128);
    split_write(d2 * rs * g[tid + 256] + be[tid + 256], Shi, Slo, base + tid + 256);
}

// ---- split-K(4) reduce + bias + relu + LN + length predictor -> lns --------
__global__ __launch_bounds__(128) void reduce_ln_pred_k(
        const _Float16* __restrict__ Pbase, size_t halfStride,
        const float* __restrict__ bias, const float* __restrict__ g,
        const float* __restrict__ be, const float* __restrict__ wl,
        const float* __restrict__ bl, const int* __restrict__ token_lengths,
        int* __restrict__ lns) {
    const int row = blockIdx.x;
    const int b = row >> 10, l = row & 1023;
    const size_t SNc = (size_t)BB * PADL * DD;
    const size_t base = (size_t)(b * PADL + 1 + l) * DD;
    const int tid = threadIdx.x;
    float v0 = bias[tid], v1 = bias[tid + 128], v2 = bias[tid + 256];
    #pragma unroll
    for (int h = 0; h < 4; ++h) {
        const _Float16* ph = Pbase + (size_t)h * halfStride;
        const _Float16* pl = ph + SNc;
        v0 += split_read(ph, pl, base + tid);
        v1 += split_read(ph, pl, base + tid + 128);
        v2 += split_read(ph, pl, base + tid + 256);
    }
    v0 = fmaxf(v0, 0.f); v1 = fmaxf(v1, 0.f); v2 = fmaxf(v2, 0.f);

    __shared__ float sh[2];
    float s = v0 + v1 + v2;
    #pragma unroll
    for (int o = 32; o > 0; o >>= 1) s += __shfl_down(s, o, 64);
    if ((tid & 63) == 0) sh[tid >> 6] = s;
    __syncthreads();
    float mu = (sh[0] + sh[1]) * (1.f / DD);
    __syncthreads();
    float d0 = v0 - mu, d1 = v1 - mu, d2 = v2 - mu;
    float q = d0 * d0 + d1 * d1 + d2 * d2;
    #pragma unroll
    for (int o = 32; o > 0; o >>= 1) q += __shfl_down(q, o, 64);
    if ((tid & 63) == 0) sh[tid >> 6] = q;
    __syncthreads();
    float var = (sh[0] + sh[1]) * (1.f / DD);
    float rs = rsqrtf(var + 1e-5f);
    __syncthreads();
    float p = (d0 * rs * g[tid]       + be[tid])       * wl[tid]
            + (d1 * rs * g[tid + 128] + be[tid + 128]) * wl[tid + 128]
            + (d2 * rs * g[tid + 256] + be[tid + 256]) * wl[tid + 256];
    #pragma unroll
    for (int o = 32; o > 0; o >>= 1) p += __shfl_down(p, o, 64);
    if ((tid & 63) == 0) sh[tid >> 6] = p;
    __syncthreads();
    if (tid == 0) {
        float pred = sh[0] + sh[1] + bl[0];
        float e = expf(pred);           // ALPHA == 1.0
        float r = rintf(e);             // round-half-even, matches jnp.round
        r = fminf(fmaxf(r, 0.f), (float)MAX_DUR);
        int v = (int)r;
        if (l >= token_lengths[b]) v = 0;
        lns[row] = v;
    }
}

// ---------------- per-batch inclusive cumsum (L=1024) ------------------------
__global__ __launch_bounds__(1024) void cumsum_k(
        const int* __restrict__ lns, int* __restrict__ csum,
        float* __restrict__ totals_out) {
    __shared__ int s[1024];
    const int b = blockIdx.x, tid = threadIdx.x;
    s[tid] = lns[(b << 10) + tid];
    __syncthreads();
    #pragma unroll
    for (int o = 1; o < 1024; o <<= 1) {
        int t = (tid >= o) ? s[tid - o] : 0;
        __syncthreads();
        s[tid] += t;
        __syncthreads();
    }
    csum[(b << 10) + tid] = s[tid];
    if (tid == 1023) totals_out[b] = (float)s[1023];
}

// ---------------- idx precompute: one search per (b,t) -----------------------
__global__ __launch_bounds__(256) void idx_k(
        const int* __restrict__ csum, int* __restrict__ idxArr) {
    int id = blockIdx.x * 256 + threadIdx.x;
    if (id >= BB * T_OUT) return;
    int b = id / T_OUT, t = id - b * T_OUT;
    const int* c = csum + (b << 10);
    int total = c[1023];
    int r = -1;
    if (t < total) {
        int lo = 0, hi = 1024;
        while (lo < hi) {               // searchsorted side='right'
            int mid = (lo + hi) >> 1;
            if (c[mid] <= t) lo = mid + 1; else hi = mid;
        }
        r = min(lo, LL - 1);
    }
    idxArr[id] = r;
}

// ---------------- gather: out[b,t,:] = idx>=0 ? y[b, idx, :] : 0 -------------
__global__ __launch_bounds__(256) void gather_k(
        const float* __restrict__ y, const int* __restrict__ idxArr,
        float* __restrict__ out) {
    int gid = blockIdx.x * 256 + threadIdx.x;   // B*T_OUT*96 float4 chunks
    int c4 = gid % 96;
    int rest = gid / 96;
    int t = rest % T_OUT;
    int b = rest / T_OUT;
    int r = idxArr[b * T_OUT + t];
    float4 v = make_float4(0.f, 0.f, 0.f, 0.f);
    if (r >= 0) v = *(const float4*)(y + ((size_t)((b << 10) + r)) * DD + (c4 << 2));
    *(float4*)(out + ((size_t)b * T_OUT + t) * DD + (c4 << 2)) = v;
}

// ---------------- host side --------------------------------------------------
extern "C" void kernel_launch(void* const* d_in, const int* in_sizes, int n_in,
                              void* d_out, int out_size, void* d_ws, size_t ws_size,
                              hipStream_t stream) {
    const float* y   = (const float*)d_in[0];
    const int*   tok = (const int*)d_in[1];
    const float* w1a = (const float*)d_in[2];
    const float* b1a = (const float*)d_in[3];
    const float* w1b = (const float*)d_in[4];
    const float* b1b = (const float*)d_in[5];
    const float* g1  = (const float*)d_in[6];
    const float* be1 = (const float*)d_in[7];
    const float* w2a = (const float*)d_in[8];
    const float* b2a = (const float*)d_in[9];
    const float* w2b = (const float*)d_in[10];
    const float* b2b = (const float*)d_in[11];
    const float* g2  = (const float*)d_in[12];
    const float* be2 = (const float*)d_in[13];
    const float* wl  = (const float*)d_in[14];
    const float* bl  = (const float*)d_in[15];

    float* out = (float*)d_out;

    // workspace layout (halfs): W (8*WN) | S (2*SN) | H1 (2*H1N)
    const size_t WN   = (size_t)FF * DD * KK;          // 1,769,472
    const size_t SN   = (size_t)BB * PADL * DD;        // 6,303,744
    const size_t H1N  = (size_t)BB * PADL * FF;        // 25,214,976
    _Float16* wsh = (_Float16*)d_ws;
    _Float16* Wh1a = wsh;            _Float16* Wl1a = Wh1a + WN;
    _Float16* Wh1b = Wl1a + WN;      _Float16* Wl1b = Wh1b + WN;
    _Float16* Wh2a = Wl1b + WN;      _Float16* Wl2a = Wh2a + WN;
    _Float16* Wh2b = Wl2a + WN;      _Float16* Wl2b = Wh2b + WN;
    _Float16* Shi  = Wl2b + WN;      _Float16* Slo  = Shi + SN;
    _Float16* H1hi = Slo + SN;       _Float16* H1lo = H1hi + H1N;
    int* lns    = (int*)(H1lo + H1N);
    int* csum   = lns + BB * LL;
    int* idxArr = csum + BB * LL;

    // split-K partials live in d_out (overwritten later by gather; the out0
    // region is 62.9M floats, partials need 50.4M halfs = 25.2M floats, and
    // the totals slot at +BB*T_OUT*DD is untouched).
    _Float16* Pbase = (_Float16*)d_out;
    const size_t halfStride = 2 * SN;                  // hi|lo per half

    const int M = BB * LL;                              // 16384

    // 1) prep: fused weight pack + fused ysplit/padzero
    prep_w<<<(4 * FF * 3 * DD) / 256, 256, 0, stream>>>(w1a, w1b, w2a, w2b, wsh);
    prep_y<<<(int)((SN + BB * 2 * FF + 255) / 256), 256, 0, stream>>>(y, Shi, Slo, H1hi, H1lo);

    const int ffBlocks = (M / 128) * (FF / 128);        // 1536 = 3 full CU-waves
    const int ddBlocksPerHalf = (M / 128) * (DD / 128); // 384; x4 halves = 1536

    // 2) block 1: FF-GEMM full-K; DD-GEMM split-K=4 -> partials in d_out; fused reduce+LN -> S
    gemm_split<<<ffBlocks, 256, 0, stream>>>(
        Shi, Slo, Wh1a, Wl1a, b1a, H1hi, H1lo, 0,
        DD, FF, (3 * DD) >> 5, FF / 128, ffBlocks, 1);
    gemm_split<<<4 * ddBlocksPerHalf, 256, 0, stream>>>(
        H1hi, H1lo, Wh1b, Wl1b, b1b, Pbase, Pbase + SN, halfStride,
        FF, DD, ((3 * FF) >> 5) / 4, DD / 128, ddBlocksPerHalf, 0);
    reduce_ln_k<<<M, 128, 0, stream>>>(Pbase, halfStride, Shi, Slo, b1b, g1, be1);

    // 3) block 2
    gemm_split<<<ffBlocks, 256, 0, stream>>>(
        Shi, Slo, Wh2a, Wl2a, b2a, H1hi, H1lo, 0,
        DD, FF, (3 * DD) >> 5, FF / 128, ffBlocks, 1);
    gemm_split<<<4 * ddBlocksPerHalf, 256, 0, stream>>>(
        H1hi, H1lo, Wh2b, Wl2b, b2b, Pbase, Pbase + SN, halfStride,
        FF, DD, ((3 * FF) >> 5) / 4, DD / 128, ddBlocksPerHalf, 0);
    reduce_ln_pred_k<<<M, 128, 0, stream>>>(Pbase, halfStride, b2b, g2, be2, wl, bl, tok, lns);

    // 4) cumsum + idx + gather (gather overwrites the partial scratch in d_out)
    cumsum_k<<<BB, 1024, 0, stream>>>(lns, csum, out + (size_t)BB * T_OUT * DD);
    idx_k<<<(BB * T_OUT + 255) / 256, 256, 0, stream>>>(csum, idxArr);
    {
        long long n = (long long)BB * T_OUT * 96;
        gather_k<<<(int)((n + 255) / 256), 256, 0, stream>>>(y, idxArr, out);
    }
}